// Round 27
// baseline (167.639 us; speedup 1.0000x reference)
//
#include <hip/hip_runtime.h>

#define K_DIM 512
#define S_DIM 64
#define T_LEN 64
#define BW    16      // sequences per workgroup
#define NWG   32      // 32 workgroups x 16 seqs = 512

typedef float f32x4 __attribute__((ext_vector_type(4)));
typedef float f32x2 __attribute__((ext_vector_type(2)));
typedef long  i64x2 __attribute__((ext_vector_type(2)));

__device__ __forceinline__ char f2fp8(float f) {   // OCP e4m3 on gfx950
    return (char)__builtin_amdgcn_cvt_pk_fp8_f32(f, f, 0, false);
}
// pack 4 floats -> 4 fp8 bytes (little-endian: a=byte0 .. d=byte3)
__device__ __forceinline__ unsigned pack4fp8(float a, float b, float c, float d) {
    unsigned v = __builtin_amdgcn_cvt_pk_fp8_f32(a, b, 0, false);
    v = __builtin_amdgcn_cvt_pk_fp8_f32(c, d, v, true);
    return v;
}

// ---------------- pre-pass: fp8 A + fp8 Ceff + packed {pi, pi*Bt} ----------------
__global__ void ssm_prep(const float* __restrict__ A, const float* __restrict__ B,
                         const float* __restrict__ C, const float* __restrict__ Pp,
                         char* __restrict__ A8, char* __restrict__ C8,
                         f32x2* __restrict__ PPB) {
    int i = blockIdx.x * blockDim.x + threadIdx.x;
    int stride = gridDim.x * blockDim.x;
    for (int idx = i; idx < K_DIM * K_DIM; idx += stride)
        A8[idx] = f2fp8(A[idx]);
    for (int idx = i; idx < S_DIM * K_DIM; idx += stride) {
        int s = idx >> 9;               // K_DIM == 512
        int k = idx & (K_DIM - 1);
        float p = 1.0f / (1.0f + expf(-Pp[idx]));
        C8[idx] = f2fp8(C[idx] * p);
        PPB[idx] = (f32x2){p, p * B[k * S_DIM + s]};   // {pi, pi*Bt[tok][k]}
    }
}

#define MFMA8(aj, bj, acc) acc = __builtin_amdgcn_mfma_f32_16x16x32_fp8_fp8(aj, bj, acc, 0, 0, 0)

// stream REMOTE macro j (K=64 chunk at remB + j*64): 4 nt-rows x dwordx4
#define LOADM(j) \
    i64x2 ga_##j = *(const i64x2*)(a8P0 + remB + (j) * 64); \
    i64x2 gb_##j = *(const i64x2*)(a8P1 + remB + (j) * 64); \
    i64x2 gc_##j = *(const i64x2*)(a8P2 + remB + (j) * 64); \
    i64x2 gd_##j = *(const i64x2*)(a8P3 + remB + (j) * 64);

// consume remote macro j (swapped: A-matrix = A-op, x = B-op); x loaded at use
#define COMPM(j) { \
    i64x2 xv = *(const i64x2*)&Xb8[p][lr][remB + (j) * 64 + 16 * lg]; \
    MFMA8(ga_##j[0], xv[0], acc0); MFMA8(ga_##j[1], xv[1], acc0); \
    MFMA8(gb_##j[0], xv[0], acc1); MFMA8(gb_##j[1], xv[1], acc1); \
    MFMA8(gc_##j[0], xv[0], acc2); MFMA8(gc_##j[1], xv[1], acc2); \
    MFMA8(gd_##j[0], xv[0], acc3); MFMA8(gd_##j[1], xv[1], acc3); }

// consume LDS-resident LOCAL macro m (0..1) with CACHED x fragment xq
#define COMPML(m, xq) { \
    i64x2 f0 = *(const i64x2*)&Aq8[w][(m)][0][l][0]; \
    i64x2 f1 = *(const i64x2*)&Aq8[w][(m)][1][l][0]; \
    i64x2 f2 = *(const i64x2*)&Aq8[w][(m)][2][l][0]; \
    i64x2 f3 = *(const i64x2*)&Aq8[w][(m)][3][l][0]; \
    MFMA8(f0[0], (xq)[0], acc0); MFMA8(f0[1], (xq)[1], acc0); \
    MFMA8(f1[0], (xq)[0], acc1); MFMA8(f1[1], (xq)[1], acc1); \
    MFMA8(f2[0], (xq)[0], acc2); MFMA8(f2[1], (xq)[1], acc2); \
    MFMA8(f3[0], (xq)[0], acc3); MFMA8(f3[1], (xq)[1], acc3); }

// consume register-resident LOCAL macro with CACHED x fragment
#define COMPR(ra, rb, rc, rd, xq) { \
    MFMA8(ra[0], (xq)[0], acc0); MFMA8(ra[1], (xq)[1], acc0); \
    MFMA8(rb[0], (xq)[0], acc1); MFMA8(rb[1], (xq)[1], acc1); \
    MFMA8(rc[0], (xq)[0], acc2); MFMA8(rc[1], (xq)[1], acc2); \
    MFMA8(rd[0], (xq)[0], acc3); MFMA8(rd[1], (xq)[1], acc3); }

// raw barrier: drain LDS ops only; wave-private vmem loads ride across
#define LBAR asm volatile("s_waitcnt lgkmcnt(0)\ns_barrier" ::: "memory")

// ---------------- main: 32 WGs x 512 threads (8 waves), 16 seqs/WG, 64 steps ----------------
// R26 + kh-RELATIVE source roles: each wave's LOCAL K-half (cols kh*256..+256)
// comes from LDS (2 macros) + loop-invariant regs (2 macros) and REUSES the
// x-fragments xq0..3 already loaded for P1 (P1's x-reads == P2's local-half
// x-operands, bit-identical). Remote half streamed as before. Per-wave LDS
// b128 reads 20 -> 16/step (-20% on the dominant LDS pipe); streams get
// ~600cy of cover (prime -> consumption spans P1 + 4 local macros).
__global__ __launch_bounds__(512) __attribute__((amdgpu_waves_per_eu(2, 2)))
void ssm_main(
    const char*  __restrict__ A8,      // [K][K] fp8 e4m3 row-major
    const char*  __restrict__ C8,      // [S][K] fp8 e4m3 (C * sigmoid(pi))
    const f32x2* __restrict__ PPB,     // [S][K] {pi, pi*Bt}
    const float* __restrict__ init,    // [K]
    const int*   __restrict__ tokens,  // [BSZ][T]
    float*       __restrict__ out)     // [BSZ]
{
    __shared__ char  Aq8[8][2][4][64][16];  // 64 KB: per-wave LOCAL macros 0,1
    __shared__ char  Xb8[2][BW][528];       // 16.9 KB fp8 state, parity buffers
    __shared__ float Lg[2][2][BW][68];      // 17.4 KB logits partials: parity x K-half
    __shared__ int   tokS[T_LEN][BW];       //  4.1 KB transposed (conflict-free reads)

    const int tid = threadIdx.x;
    const int w  = tid >> 6;     // wave 0..7, owns k-range [w*64, w*64+64)
    const int l  = tid & 63;
    const int lg = l >> 4;
    const int lr = l & 15;
    const int b0 = blockIdx.x * BW;

    for (int idx = tid; idx < BW * T_LEN; idx += 512) {
        int r = idx >> 6, t = idx & 63;
        tokS[t][r] = tokens[(b0 + r) * T_LEN + t];
    }
    for (int idx = tid; idx < BW * K_DIM; idx += 512) {
        int r = idx >> 9, k = idx & (K_DIM - 1);
        Xb8[0][r][k] = f2fp8(init[k]);
    }
    // stage each wave's LOCAL macros 0,1 (cols kh(w)*256 + {0,64}) into LDS
    for (int idx = tid; idx < 4096; idx += 512) {
        int w2 = idx >> 9, rem = idx & 511;
        int m2 = rem >> 8, rem2 = rem & 255;
        int q2 = rem2 >> 6, l2 = rem2 & 63;
        int col = (w2 >> 2) * 256 + m2 * 64;
        *(i64x2*)&Aq8[w2][m2][q2][l2][0] =
            *(const i64x2*)(A8 + (w2 * 64 + q2 * 16 + (l2 & 15)) * K_DIM
                            + col + (l2 >> 4) * 16);
    }
    // fp32 master state: xm[nt][e] = x[seq=lr][k = w*64+nt*16+4*lg+e]
    float xm[4][4];
    #pragma unroll
    for (int nt = 0; nt < 4; ++nt) {
        #pragma unroll
        for (int e = 0; e < 4; ++e)
            xm[nt][e] = init[w * 64 + nt * 16 + 4 * lg + e];
    }

    const int sq = w & 3;            // logits s-tile
    const int kh = w >> 2;           // logits K-half (== local half)
    const int locB = kh * 256;       // local-half byte base in k
    const int remB = 256 - locB;     // remote-half byte base

    // per-lane fp8 A bases (one per nt-quarter of the wave's 64 rows)
    const char* a8P0 = A8 + (w * 64 +      lr) * K_DIM + 16 * lg;
    const char* a8P1 = A8 + (w * 64 + 16 + lr) * K_DIM + 16 * lg;
    const char* a8P2 = A8 + (w * 64 + 32 + lr) * K_DIM + 16 * lg;
    const char* a8P3 = A8 + (w * 64 + 48 + lr) * K_DIM + 16 * lg;
    const char* c8P  = C8 + (sq * 16 + lr) * K_DIM + locB + 16 * lg;

    // LOCAL macros 2,3 resident in loop-invariant VGPRs (32 regs, loaded ONCE)
    const i64x2 r2a = *(const i64x2*)(a8P0 + locB + 128);
    const i64x2 r2b = *(const i64x2*)(a8P1 + locB + 128);
    const i64x2 r2c = *(const i64x2*)(a8P2 + locB + 128);
    const i64x2 r2d = *(const i64x2*)(a8P3 + locB + 128);
    const i64x2 r3a = *(const i64x2*)(a8P0 + locB + 192);
    const i64x2 r3b = *(const i64x2*)(a8P1 + locB + 192);
    const i64x2 r3c = *(const i64x2*)(a8P2 + locB + 192);
    const i64x2 r3d = *(const i64x2*)(a8P3 + locB + 192);

    float llacc = 0.0f;
    __syncthreads();

    for (int t = 0; t < T_LEN; ++t) {
        const int p = t & 1;

        // ---- prime remote macros 0,1; latency hides under P1 + local P2
        LOADM(0) LOADM(1)

        // ---- P1: logits partial (local K-half), x-fragments CACHED as xq0..3
        i64x2 xq0 = *(const i64x2*)&Xb8[p][lr][locB +   0 + 16 * lg];
        i64x2 xq1 = *(const i64x2*)&Xb8[p][lr][locB +  64 + 16 * lg];
        i64x2 xq2 = *(const i64x2*)&Xb8[p][lr][locB + 128 + 16 * lg];
        i64x2 xq3 = *(const i64x2*)&Xb8[p][lr][locB + 192 + 16 * lg];
        f32x4 lga = {0.f, 0.f, 0.f, 0.f};
        {
            i64x2 cv0 = *(const i64x2*)(c8P +   0);
            i64x2 cv1 = *(const i64x2*)(c8P +  64);
            i64x2 cv2 = *(const i64x2*)(c8P + 128);
            i64x2 cv3 = *(const i64x2*)(c8P + 192);
            MFMA8(xq0[0], cv0[0], lga); MFMA8(xq0[1], cv0[1], lga);
            MFMA8(xq1[0], cv1[0], lga); MFMA8(xq1[1], cv1[1], lga);
            MFMA8(xq2[0], cv2[0], lga); MFMA8(xq2[1], cv2[1], lga);
            MFMA8(xq3[0], cv3[0], lga); MFMA8(xq3[1], cv3[1], lga);
        }
        #pragma unroll
        for (int e = 0; e < 4; ++e)
            Lg[p][kh][4 * lg + e][sq * 16 + lr] = lga[e];

        // ---- P2a: LOCAL half from LDS/regs, reusing xq0..3 (no new x-reads)
        f32x4 acc0 = {0.f, 0.f, 0.f, 0.f};
        f32x4 acc1 = {0.f, 0.f, 0.f, 0.f};
        f32x4 acc2 = {0.f, 0.f, 0.f, 0.f};
        f32x4 acc3 = {0.f, 0.f, 0.f, 0.f};
        COMPML(0, xq0)
        COMPML(1, xq1)
        COMPR(r2a, r2b, r2c, r2d, xq2)
        COMPR(r3a, r3b, r3c, r3d, xq3)

        // ---- issue remote macros 2,3 + gating gathers (FIFO-safe: ppv after)
        LOADM(2) LOADM(3)
        int mytok = tokS[t][lr];
        f32x4 ppv[4][2];   // ppv[nt][h]: {pi(e),pb(e),pi(e+1),pb(e+1)}, e=2h
        #pragma unroll
        for (int nt = 0; nt < 4; ++nt) {
            const f32x2* pp = PPB + mytok * K_DIM + w * 64 + nt * 16 + 4 * lg;
            ppv[nt][0] = *(const f32x4*)(pp);
            ppv[nt][1] = *(const f32x4*)(pp + 2);
        }

        // ---- deferred softmax for step t-1 (VALU; overlaps COMPM MFMAs below)
        if (t > 0 && w < 4) {
            int b = w * 4 + (l >> 4);
            int i = l & 15;
            f32x4 v0 = *(const f32x4*)&Lg[1 - p][0][b][i * 4];
            f32x4 v1 = *(const f32x4*)&Lg[1 - p][1][b][i * 4];
            float v[4];
            #pragma unroll
            for (int c = 0; c < 4; ++c) v[c] = v0[c] + v1[c];
            float m = fmaxf(fmaxf(v[0], v[1]), fmaxf(v[2], v[3]));
            m = fmaxf(m, __shfl_xor(m, 1));
            m = fmaxf(m, __shfl_xor(m, 2));
            m = fmaxf(m, __shfl_xor(m, 4));
            m = fmaxf(m, __shfl_xor(m, 8));
            float sum = expf(v[0] - m) + expf(v[1] - m) + expf(v[2] - m) + expf(v[3] - m);
            sum += __shfl_xor(sum, 1);
            sum += __shfl_xor(sum, 2);
            sum += __shfl_xor(sum, 4);
            sum += __shfl_xor(sum, 8);
            int tok = tokS[t - 1][b];
            float sel = (i == (tok >> 2)) ? v[tok & 3] : 0.0f;
            sel += __shfl_xor(sel, 1);
            sel += __shfl_xor(sel, 2);
            sel += __shfl_xor(sel, 4);
            sel += __shfl_xor(sel, 8);
            llacc += sel - m - logf(sum);
        }

        // ---- P2b: REMOTE half streamed (macros 0,1 long landed; 2,3 covered)
        COMPM(0) COMPM(1) COMPM(2) COMPM(3)

        // ---- P3: gating in fp32; write Xb8[1-p] (no WAR with readers of [p])
        #pragma unroll
        for (int nt = 0; nt < 4; ++nt) {
            f32x4 a = (nt == 0) ? acc0 : (nt == 1) ? acc1 : (nt == 2) ? acc2 : acc3;
            float nx0 = xm[nt][0] + ppv[nt][0][0] * (a[0] - xm[nt][0]) + ppv[nt][0][1];
            float nx1 = xm[nt][1] + ppv[nt][0][2] * (a[1] - xm[nt][1]) + ppv[nt][0][3];
            float nx2 = xm[nt][2] + ppv[nt][1][0] * (a[2] - xm[nt][2]) + ppv[nt][1][1];
            float nx3 = xm[nt][3] + ppv[nt][1][2] * (a[3] - xm[nt][3]) + ppv[nt][1][3];
            xm[nt][0] = nx0; xm[nt][1] = nx1; xm[nt][2] = nx2; xm[nt][3] = nx3;
            *(unsigned*)&Xb8[1 - p][lr][w * 64 + nt * 16 + 4 * lg] = pack4fp8(nx0, nx1, nx2, nx3);
        }
        LBAR;   // single barrier: Xb8[1-p] + Lg[p] visible for next step
    }

    // epilogue: softmax for the last step (t = 63, parity 1 -> Lg[1])
    if (w < 4) {
        int b = w * 4 + (l >> 4);
        int i = l & 15;
        f32x4 v0 = *(const f32x4*)&Lg[1][0][b][i * 4];
        f32x4 v1 = *(const f32x4*)&Lg[1][1][b][i * 4];
        float v[4];
        #pragma unroll
        for (int c = 0; c < 4; ++c) v[c] = v0[c] + v1[c];
        float m = fmaxf(fmaxf(v[0], v[1]), fmaxf(v[2], v[3]));
        m = fmaxf(m, __shfl_xor(m, 1));
        m = fmaxf(m, __shfl_xor(m, 2));
        m = fmaxf(m, __shfl_xor(m, 4));
        m = fmaxf(m, __shfl_xor(m, 8));
        float sum = expf(v[0] - m) + expf(v[1] - m) + expf(v[2] - m) + expf(v[3] - m);
        sum += __shfl_xor(sum, 1);
        sum += __shfl_xor(sum, 2);
        sum += __shfl_xor(sum, 4);
        sum += __shfl_xor(sum, 8);
        int tok = tokS[T_LEN - 1][b];
        float sel = (i == (tok >> 2)) ? v[tok & 3] : 0.0f;
        sel += __shfl_xor(sel, 1);
        sel += __shfl_xor(sel, 2);
        sel += __shfl_xor(sel, 4);
        sel += __shfl_xor(sel, 8);
        llacc += sel - m - logf(sum);

        if ((l & 15) == 0)
            out[b0 + w * 4 + (l >> 4)] = llacc;
    }
}

extern "C" void kernel_launch(void* const* d_in, const int* in_sizes, int n_in,
                              void* d_out, int out_size, void* d_ws, size_t ws_size,
                              hipStream_t stream) {
    const float* A  = (const float*)d_in[0];   // (512,512)
    const float* B  = (const float*)d_in[1];   // (512,64)
    const float* C  = (const float*)d_in[2];   // (64,512)
    const float* Pp = (const float*)d_in[3];   // (64,512)
    const float* init = (const float*)d_in[4]; // (512,)
    const int* tokens = (const int*)d_in[5];   // (512,64)
    float* out = (float*)d_out;

    // workspace layout (needs 557,056 bytes)
    char*  A8  = (char*)d_ws;                                  // 512*512*1 = 262144
    char*  C8  = (char*)d_ws + 262144;                         // 64*512*1  =  32768
    f32x2* PPB = (f32x2*)((char*)d_ws + 294912);               // 64*512*8  = 262144

    ssm_prep<<<256, 256, 0, stream>>>(A, B, C, Pp, A8, C8, PPB);
    ssm_main<<<NWG, 512, 0, stream>>>(A8, C8, PPB, init, tokens, out);
}

// Round 28
// 160.650 us; speedup vs baseline: 1.0435x; 1.0435x over previous
//
#include <hip/hip_runtime.h>

#define K_DIM 512
#define S_DIM 64
#define T_LEN 64
#define BW    16      // sequences per workgroup
#define NWG   32      // 32 workgroups x 16 seqs = 512

typedef float f32x4 __attribute__((ext_vector_type(4)));
typedef float f32x2 __attribute__((ext_vector_type(2)));
typedef long  i64x2 __attribute__((ext_vector_type(2)));

__device__ __forceinline__ char f2fp8(float f) {   // OCP e4m3 on gfx950
    return (char)__builtin_amdgcn_cvt_pk_fp8_f32(f, f, 0, false);
}
// pack 4 floats -> 4 fp8 bytes (little-endian: a=byte0 .. d=byte3)
__device__ __forceinline__ unsigned pack4fp8(float a, float b, float c, float d) {
    unsigned v = __builtin_amdgcn_cvt_pk_fp8_f32(a, b, 0, false);
    v = __builtin_amdgcn_cvt_pk_fp8_f32(c, d, v, true);
    return v;
}

// ---------------- pre-pass: fp8 A + fp8 Ceff + packed {pi, pi*Bt} ----------------
__global__ void ssm_prep(const float* __restrict__ A, const float* __restrict__ B,
                         const float* __restrict__ C, const float* __restrict__ Pp,
                         char* __restrict__ A8, char* __restrict__ C8,
                         f32x2* __restrict__ PPB) {
    int i = blockIdx.x * blockDim.x + threadIdx.x;
    int stride = gridDim.x * blockDim.x;
    for (int idx = i; idx < K_DIM * K_DIM; idx += stride)
        A8[idx] = f2fp8(A[idx]);
    for (int idx = i; idx < S_DIM * K_DIM; idx += stride) {
        int s = idx >> 9;               // K_DIM == 512
        int k = idx & (K_DIM - 1);
        float p = 1.0f / (1.0f + expf(-Pp[idx]));
        C8[idx] = f2fp8(C[idx] * p);
        PPB[idx] = (f32x2){p, p * B[k * S_DIM + s]};   // {pi, pi*Bt[tok][k]}
    }
}

#define MFMA8(aj, bj, acc) acc = __builtin_amdgcn_mfma_f32_16x16x32_fp8_fp8(aj, bj, acc, 0, 0, 0)

// stream macro-slice m (K=64 chunk): 4 nt-rows x dwordx4 (16 fp8 = 2 k-slices)
#define LOADM(m) \
    i64x2 ga_##m = *(const i64x2*)(a8P0 + (m) * 64); \
    i64x2 gb_##m = *(const i64x2*)(a8P1 + (m) * 64); \
    i64x2 gc_##m = *(const i64x2*)(a8P2 + (m) * 64); \
    i64x2 gd_##m = *(const i64x2*)(a8P3 + (m) * 64);

// consume macro m: SWAPPED operand order (A-matrix = A-operand, x = B-operand)
// -> D[row=4lg+e -> k_out][col=lr -> seq]: thread owns seq=lr, 4 consecutive k
#define COMPM(m) { \
    i64x2 xv = *(const i64x2*)&Xb8[lr][(m) * 64 + 16 * lg]; \
    MFMA8(ga_##m[0], xv[0], acc0); MFMA8(ga_##m[1], xv[1], acc0); \
    MFMA8(gb_##m[0], xv[0], acc1); MFMA8(gb_##m[1], xv[1], acc1); \
    MFMA8(gc_##m[0], xv[0], acc2); MFMA8(gc_##m[1], xv[1], acc2); \
    MFMA8(gd_##m[0], xv[0], acc3); MFMA8(gd_##m[1], xv[1], acc3); }

// consume LDS-resident macro m (4..5), swapped order
#define COMPML(m) { \
    i64x2 xv = *(const i64x2*)&Xb8[lr][(m) * 64 + 16 * lg]; \
    i64x2 f0 = *(const i64x2*)&Aq8[w][(m) - 4][0][l][0]; \
    i64x2 f1 = *(const i64x2*)&Aq8[w][(m) - 4][1][l][0]; \
    i64x2 f2 = *(const i64x2*)&Aq8[w][(m) - 4][2][l][0]; \
    i64x2 f3 = *(const i64x2*)&Aq8[w][(m) - 4][3][l][0]; \
    MFMA8(f0[0], xv[0], acc0); MFMA8(f0[1], xv[1], acc0); \
    MFMA8(f1[0], xv[0], acc1); MFMA8(f1[1], xv[1], acc1); \
    MFMA8(f2[0], xv[0], acc2); MFMA8(f2[1], xv[1], acc2); \
    MFMA8(f3[0], xv[0], acc3); MFMA8(f3[1], xv[1], acc3); }

// consume register-resident macros 6,7 (loop-invariant VGPRs, loaded once)
#define COMPR(m, ra, rb, rc, rd) { \
    i64x2 xv = *(const i64x2*)&Xb8[lr][(m) * 64 + 16 * lg]; \
    MFMA8(ra[0], xv[0], acc0); MFMA8(ra[1], xv[1], acc0); \
    MFMA8(rb[0], xv[0], acc1); MFMA8(rb[1], xv[1], acc1); \
    MFMA8(rc[0], xv[0], acc2); MFMA8(rc[1], xv[1], acc2); \
    MFMA8(rd[0], xv[0], acc3); MFMA8(rd[1], xv[1], acc3); }

// raw barrier: drain LDS ops only; wave-private vmem loads ride across
#define LBAR asm volatile("s_waitcnt lgkmcnt(0)\ns_barrier" ::: "memory")

// ---------------- main: 32 WGs x 512 threads (8 waves), 16 seqs/WG, 64 steps ----------------
// Final kernel == R25 (best measured: 160.3us, absmax 16.0). Structure:
// fp8 MFMA both GEMMs, fp32 master state; macros 0..3 streamed depth-2 through
// VGPRs, 4..5 LDS-resident, 6..7 loop-invariant VGPRs; swapped P2 operand
// order (thread owns seq=lr, 4 consecutive k -> vector gating/pack/ds_write);
// deferred softmax overlapped with MFMA cluster; transposed tokS; b128 Lg.
__global__ __launch_bounds__(512) __attribute__((amdgpu_waves_per_eu(2, 2)))
void ssm_main(
    const char*  __restrict__ A8,      // [K][K] fp8 e4m3 row-major
    const char*  __restrict__ C8,      // [S][K] fp8 e4m3 (C * sigmoid(pi))
    const f32x2* __restrict__ PPB,     // [S][K] {pi, pi*Bt}
    const float* __restrict__ init,    // [K]
    const int*   __restrict__ tokens,  // [BSZ][T]
    float*       __restrict__ out)     // [BSZ]
{
    __shared__ char  Aq8[8][2][4][64][16];  // 64 KB: A cols 256..384 fp8, fragment order
    __shared__ char  Xb8[BW][528];          //  8.4 KB fp8 state (both GEMM paths)
    __shared__ float Lg[2][2][BW][68];      // 17.4 KB logits partials: parity x K-half
    __shared__ int   tokS[T_LEN][BW];       //  4.1 KB transposed (conflict-free reads)

    const int tid = threadIdx.x;
    const int w  = tid >> 6;     // wave 0..7, owns k-range [w*64, w*64+64)
    const int l  = tid & 63;
    const int lg = l >> 4;
    const int lr = l & 15;
    const int b0 = blockIdx.x * BW;

    for (int idx = tid; idx < BW * T_LEN; idx += 512) {
        int r = idx >> 6, t = idx & 63;
        tokS[t][r] = tokens[(b0 + r) * T_LEN + t];
    }
    for (int idx = tid; idx < BW * K_DIM; idx += 512) {
        int r = idx >> 9, k = idx & (K_DIM - 1);
        Xb8[r][k] = f2fp8(init[k]);
    }
    // stage A fp8 macros 4..5 into LDS in fragment order (once; reused 64 steps)
    for (int idx = tid; idx < 4096; idx += 512) {
        int w2 = idx >> 9, rem = idx & 511;
        int m2 = rem >> 8, rem2 = rem & 255;
        int q2 = rem2 >> 6, l2 = rem2 & 63;
        *(i64x2*)&Aq8[w2][m2][q2][l2][0] =
            *(const i64x2*)(A8 + (w2 * 64 + q2 * 16 + (l2 & 15)) * K_DIM
                            + (4 + m2) * 64 + (l2 >> 4) * 16);
    }
    // fp32 master state: xm[nt][e] = x[seq=lr][k = w*64+nt*16+4*lg+e]
    float xm[4][4];
    #pragma unroll
    for (int nt = 0; nt < 4; ++nt) {
        #pragma unroll
        for (int e = 0; e < 4; ++e)
            xm[nt][e] = init[w * 64 + nt * 16 + 4 * lg + e];
    }

    const int sq = w & 3;    // logits s-tile
    const int kh = w >> 2;   // logits K-half

    // per-lane fp8 A bases (one per nt-quarter of the wave's 64 rows)
    const char* a8P0 = A8 + (w * 64 +      lr) * K_DIM + 16 * lg;
    const char* a8P1 = A8 + (w * 64 + 16 + lr) * K_DIM + 16 * lg;
    const char* a8P2 = A8 + (w * 64 + 32 + lr) * K_DIM + 16 * lg;
    const char* a8P3 = A8 + (w * 64 + 48 + lr) * K_DIM + 16 * lg;
    const char* c8P  = C8 + (sq * 16 + lr) * K_DIM + kh * 256 + 16 * lg;

    // macros 6,7 resident in loop-invariant VGPRs (32 regs, loaded ONCE)
    const i64x2 r6a = *(const i64x2*)(a8P0 + 6 * 64);
    const i64x2 r6b = *(const i64x2*)(a8P1 + 6 * 64);
    const i64x2 r6c = *(const i64x2*)(a8P2 + 6 * 64);
    const i64x2 r6d = *(const i64x2*)(a8P3 + 6 * 64);
    const i64x2 r7a = *(const i64x2*)(a8P0 + 7 * 64);
    const i64x2 r7b = *(const i64x2*)(a8P1 + 7 * 64);
    const i64x2 r7c = *(const i64x2*)(a8P2 + 7 * 64);
    const i64x2 r7d = *(const i64x2*)(a8P3 + 7 * 64);

    float llacc = 0.0f;
    __syncthreads();

    for (int t = 0; t < T_LEN; ++t) {
        const int p = t & 1;

        // ---- prime 2 macro-slices; latency hides under P1
        LOADM(0) LOADM(1)

        // ---- P1: logits partial GEMM (K-half kh), fp8, unswapped (x = A-op)
        f32x4 lga = {0.f, 0.f, 0.f, 0.f};
        #pragma unroll
        for (int j = 0; j < 4; ++j) {
            i64x2 cv = *(const i64x2*)(c8P + j * 64);
            i64x2 xv = *(const i64x2*)&Xb8[lr][kh * 256 + j * 64 + 16 * lg];
            MFMA8(xv[0], cv[0], lga);
            MFMA8(xv[1], cv[1], lga);
        }
        #pragma unroll
        for (int e = 0; e < 4; ++e)
            Lg[p][kh][4 * lg + e][sq * 16 + lr] = lga[e];

        // ---- P2: update GEMM fp8 (swapped), macros 0..3 streamed depth-2
        f32x4 acc0 = {0.f, 0.f, 0.f, 0.f};
        f32x4 acc1 = {0.f, 0.f, 0.f, 0.f};
        f32x4 acc2 = {0.f, 0.f, 0.f, 0.f};
        f32x4 acc3 = {0.f, 0.f, 0.f, 0.f};
        COMPM(0)  LOADM(2)
        COMPM(1)  LOADM(3)
        COMPM(2)
        COMPM(3)
        // ---- gating gathers: 1 token/thread, 8 contiguous f32x4 loads
        int mytok = tokS[t][lr];
        f32x4 ppv[4][2];   // ppv[nt][h]: {pi(e),pb(e),pi(e+1),pb(e+1)}, e=2h
        #pragma unroll
        for (int nt = 0; nt < 4; ++nt) {
            const f32x2* pp = PPB + mytok * K_DIM + w * 64 + nt * 16 + 4 * lg;
            ppv[nt][0] = *(const f32x4*)(pp);
            ppv[nt][1] = *(const f32x4*)(pp + 2);
        }

        // ---- deferred softmax for step t-1 (reads Lg[1-p] via 2x b128,
        //      conflict-free); overlaps with COMPML/COMPR MFMAs below
        if (t > 0 && w < 4) {
            int b = w * 4 + (l >> 4);
            int i = l & 15;
            f32x4 v0 = *(const f32x4*)&Lg[1 - p][0][b][i * 4];
            f32x4 v1 = *(const f32x4*)&Lg[1 - p][1][b][i * 4];
            float v[4];
            #pragma unroll
            for (int c = 0; c < 4; ++c) v[c] = v0[c] + v1[c];
            float m = fmaxf(fmaxf(v[0], v[1]), fmaxf(v[2], v[3]));
            m = fmaxf(m, __shfl_xor(m, 1));
            m = fmaxf(m, __shfl_xor(m, 2));
            m = fmaxf(m, __shfl_xor(m, 4));
            m = fmaxf(m, __shfl_xor(m, 8));
            float sum = expf(v[0] - m) + expf(v[1] - m) + expf(v[2] - m) + expf(v[3] - m);
            sum += __shfl_xor(sum, 1);
            sum += __shfl_xor(sum, 2);
            sum += __shfl_xor(sum, 4);
            sum += __shfl_xor(sum, 8);
            int tok = tokS[t - 1][b];
            float sel = (i == (tok >> 2)) ? v[tok & 3] : 0.0f;
            sel += __shfl_xor(sel, 1);
            sel += __shfl_xor(sel, 2);
            sel += __shfl_xor(sel, 4);
            sel += __shfl_xor(sel, 8);
            llacc += sel - m - logf(sum);
        }

        // ---- macros 4..5 from LDS, macros 6,7 from registers
        COMPML(4) COMPML(5)
        COMPR(6, r6a, r6b, r6c, r6d)
        COMPR(7, r7a, r7b, r7c, r7d)
        LBAR;   // barrier1: Xb8 reads done, Lg[p] visible

        // ---- P3: gating in fp32; thread owns seq=lr, 4 consecutive k per nt
        #pragma unroll
        for (int nt = 0; nt < 4; ++nt) {
            f32x4 a = (nt == 0) ? acc0 : (nt == 1) ? acc1 : (nt == 2) ? acc2 : acc3;
            float nx0 = xm[nt][0] + ppv[nt][0][0] * (a[0] - xm[nt][0]) + ppv[nt][0][1];
            float nx1 = xm[nt][1] + ppv[nt][0][2] * (a[1] - xm[nt][1]) + ppv[nt][0][3];
            float nx2 = xm[nt][2] + ppv[nt][1][0] * (a[2] - xm[nt][2]) + ppv[nt][1][1];
            float nx3 = xm[nt][3] + ppv[nt][1][2] * (a[3] - xm[nt][3]) + ppv[nt][1][3];
            xm[nt][0] = nx0; xm[nt][1] = nx1; xm[nt][2] = nx2; xm[nt][3] = nx3;
            *(unsigned*)&Xb8[lr][w * 64 + nt * 16 + 4 * lg] = pack4fp8(nx0, nx1, nx2, nx3);
        }
        LBAR;   // barrier2: new Xb8 visible, Lg[1-p] free for overwrite
    }

    // epilogue: softmax for the last step (t = 63, parity 1 -> Lg[1])
    if (w < 4) {
        int b = w * 4 + (l >> 4);
        int i = l & 15;
        f32x4 v0 = *(const f32x4*)&Lg[1][0][b][i * 4];
        f32x4 v1 = *(const f32x4*)&Lg[1][1][b][i * 4];
        float v[4];
        #pragma unroll
        for (int c = 0; c < 4; ++c) v[c] = v0[c] + v1[c];
        float m = fmaxf(fmaxf(v[0], v[1]), fmaxf(v[2], v[3]));
        m = fmaxf(m, __shfl_xor(m, 1));
        m = fmaxf(m, __shfl_xor(m, 2));
        m = fmaxf(m, __shfl_xor(m, 4));
        m = fmaxf(m, __shfl_xor(m, 8));
        float sum = expf(v[0] - m) + expf(v[1] - m) + expf(v[2] - m) + expf(v[3] - m);
        sum += __shfl_xor(sum, 1);
        sum += __shfl_xor(sum, 2);
        sum += __shfl_xor(sum, 4);
        sum += __shfl_xor(sum, 8);
        int tok = tokS[T_LEN - 1][b];
        float sel = (i == (tok >> 2)) ? v[tok & 3] : 0.0f;
        sel += __shfl_xor(sel, 1);
        sel += __shfl_xor(sel, 2);
        sel += __shfl_xor(sel, 4);
        sel += __shfl_xor(sel, 8);
        llacc += sel - m - logf(sum);

        if ((l & 15) == 0)
            out[b0 + w * 4 + (l >> 4)] = llacc;
    }
}

extern "C" void kernel_launch(void* const* d_in, const int* in_sizes, int n_in,
                              void* d_out, int out_size, void* d_ws, size_t ws_size,
                              hipStream_t stream) {
    const float* A  = (const float*)d_in[0];   // (512,512)
    const float* B  = (const float*)d_in[1];   // (512,64)
    const float* C  = (const float*)d_in[2];   // (64,512)
    const float* Pp = (const float*)d_in[3];   // (64,512)
    const float* init = (const float*)d_in[4]; // (512,)
    const int* tokens = (const int*)d_in[5];   // (512,64)
    float* out = (float*)d_out;

    // workspace layout (needs 557,056 bytes)
    char*  A8  = (char*)d_ws;                                  // 512*512*1 = 262144
    char*  C8  = (char*)d_ws + 262144;                         // 64*512*1  =  32768
    f32x2* PPB = (f32x2*)((char*)d_ws + 294912);               // 64*512*8  = 262144

    ssm_prep<<<256, 256, 0, stream>>>(A, B, C, Pp, A8, C8, PPB);
    ssm_main<<<NWG, 512, 0, stream>>>(A8, C8, PPB, init, tokens, out);
}